// Round 1
// baseline (100.465 us; speedup 1.0000x reference)
//
#include <hip/hip_runtime.h>

#define NK 21      // classes
#define NC 256     // channels
#define NSRC 64    // source h/w
#define NOUT 256   // mask h/w
#define NB 8       // batch
#define NSL 64     // producer slices per image: one per source row (full width)
#define NG 8       // finalA slice-groups (NSL/8 per group)
#define EPS 1e-6f

// Native LDS fp32 atomic add (ds_add_f32). Plain atomicAdd(float*) lowers to
// a CAS loop.
__device__ __forceinline__ void lds_fadd(float* p, float v) {
  __hip_atomic_fetch_add(p, v, __ATOMIC_RELAXED, __HIP_MEMORY_SCOPE_WORKGROUP);
}

__device__ __forceinline__ float d4(float s, float4 a, float4 w) {
  s = fmaf(a.x, w.x, s); s = fmaf(a.y, w.y, s);
  s = fmaf(a.z, w.z, s); return fmaf(a.w, w.w, s);
}

// ---------------------------------------------------------------------------
// Main kernel. Grid (64, NB): one FULL source row per 256-thread block.
// Wave w: column-half z = w>>1; lane owns channel PAIR c0=(w&1)*128+2*lane.
//  - 2 channels/lane halves the per-unit-work LDS broadcast reads of W
//    (each 8xb128 W read now feeds 64 FMAs instead of 32).
//  - thread = fixed output column x: mask loads coalesce to 1KB rows, all
//    row-tap predicates are wave-uniform (scalar branches), no idiv.
//  - waves 2,3 (z=1) pair-reduce into waves 0,1 through LDS: psum halves
//    to [B][64][K][C] (11 MB instead of 22 MB round-trip).
// ---------------------------------------------------------------------------
__global__ __launch_bounds__(256, 2)
void proto_main(const float* __restrict__ feats,
                const int* __restrict__ masks,
                float* __restrict__ psum,   // [B][NSL][K][C]
                float* __restrict__ pcnt) { // [B][NSL][K]
  __shared__ __align__(16) float Wl[NK * 64];   // [k][src col] adjoint weights
  __shared__ __align__(16) float Red[NK * NC];  // z-half exchange buffer
  __shared__ int hist[NK];

  const int tid = threadIdx.x;
  const int r0 = blockIdx.x;   // source row 0..63
  const int bi = blockIdx.y;   // image
  const int w = tid >> 6;      // wave 0..3
  const int l = tid & 63;
  const int z = w >> 1;                       // column half 0/1
  const int c0 = ((w & 1) << 7) | (l << 1);   // channel pair base

  // ---- Phase 0a: prefetch the 8-row mask window (thread = column x) ----
  int ylo = 4 * r0 - 2; if (ylo < 0) ylo = 0;
  int yhi = 4 * r0 + 5; if (yhi > NOUT - 1) yhi = NOUT - 1;
  const int nr = yhi - ylo + 1;   // 6..8
  const int x = tid;              // fixed output column per thread
  int lab[8];
#pragma unroll
  for (int j = 0; j < 8; ++j)
    lab[j] = (j < nr) ? masks[((size_t)bi * NOUT + ylo + j) * NOUT + x] : NK;

  // ---- Phase 0b: feats prefetch: channels c0, c0+1, cols [32z, 32z+32) ----
  const float4* fA = (const float4*)(feats + (((size_t)(bi * NC + c0)) << 12) +
                                     (size_t)r0 * 64 + 32 * z);
  const float4* fB = (const float4*)((const float*)fA + 4096);  // channel c0+1
  const float4 a0 = fA[0], a1 = fA[1], a2 = fA[2], a3 = fA[3];
  const float4 a4 = fA[4], a5 = fA[5], a6 = fA[6], a7 = fA[7];
  const float4 e0 = fB[0], e1 = fB[1], e2 = fB[2], e3 = fB[3];
  const float4 e4 = fB[4], e5 = fB[5], e6 = fB[6], e7 = fB[7];

  for (int i = tid; i < NK * 64; i += 256) Wl[i] = 0.f;
  if (tid < NK) hist[tid] = 0;
  __syncthreads();

  // ---- Phase 1: bilinear-adjoint weights W[21][64] in LDS ----
  // column taps (fixed per thread, hoisted out of the row loop)
  const int rx = x >> 2, px = x & 3;
  const int j0x = (px < 2) ? rx - 1 : rx;
  const float fx = (px == 0) ? 0.625f : (px == 1) ? 0.875f
                 : (px == 2) ? 0.125f : 0.375f;
  const int cx0 = (j0x < 0) ? 0 : j0x;
  const int cx1 = (j0x + 1 > NSRC - 1) ? NSRC - 1 : j0x + 1;
  const float wx0 = 1.f - fx, wx1 = fx;

#pragma unroll
  for (int j = 0; j < 8; ++j) {
    if (j < nr) {                 // wave-uniform
      const int y = ylo + j;
      const int lbl = lab[j];
      if ((unsigned)lbl < NK) {
        const int ry = y >> 2, py = y & 3;
        const int j0y = (py < 2) ? ry - 1 : ry;
        const float fy = (py == 0) ? 0.625f : (py == 1) ? 0.875f
                       : (py == 2) ? 0.125f : 0.375f;
        const int ry0 = (j0y < 0) ? 0 : j0y;
        const int ry1 = (j0y + 1 > NSRC - 1) ? NSRC - 1 : j0y + 1;
        float* Wk = &Wl[lbl << 6];
        if (ry0 == r0) {          // wave-uniform row predicate
          lds_fadd(&Wk[cx0], (1.f - fy) * wx0);
          lds_fadd(&Wk[cx1], (1.f - fy) * wx1);
        }
        if (ry1 == r0) {          // wave-uniform row predicate
          lds_fadd(&Wk[cx0], fy * wx0);
          lds_fadd(&Wk[cx1], fy * wx1);
        }
        if ((unsigned)(y - 4 * r0) < 4u)   // ownership rows 4r0..4r0+3
          atomicAdd(&hist[lbl], 1);        // int: native ds_add
      }
    }
  }
  __syncthreads();

  // ---- Phase 2: acc[k][2ch] = sum_s W[k][32z+s] * F[ch][s] ----
  float accA[NK], accB[NK];
#pragma unroll
  for (int k = 0; k < NK; ++k) { accA[k] = 0.f; accB[k] = 0.f; }

  const float4* wb = (const float4*)&Wl[z * 32];  // k stride = 16 float4
#pragma unroll
  for (int k = 0; k < NK; ++k) {
    const float4 w0 = wb[k * 16 + 0], w1 = wb[k * 16 + 1];
    const float4 w2 = wb[k * 16 + 2], w3 = wb[k * 16 + 3];
    const float4 w4 = wb[k * 16 + 4], w5 = wb[k * 16 + 5];
    const float4 w6 = wb[k * 16 + 6], w7 = wb[k * 16 + 7];
    float sA = accA[k];
    sA = d4(sA, a0, w0); sA = d4(sA, a1, w1); sA = d4(sA, a2, w2); sA = d4(sA, a3, w3);
    sA = d4(sA, a4, w4); sA = d4(sA, a5, w5); sA = d4(sA, a6, w6); sA = d4(sA, a7, w7);
    accA[k] = sA;
    float sB = accB[k];
    sB = d4(sB, e0, w0); sB = d4(sB, e1, w1); sB = d4(sB, e2, w2); sB = d4(sB, e3, w3);
    sB = d4(sB, e4, w4); sB = d4(sB, e5, w5); sB = d4(sB, e6, w6); sB = d4(sB, e7, w7);
    accB[k] = sB;
  }

  // ---- z-half pair reduction (waves 2,3 -> 0,1) + coalesced store ----
  if (w >= 2) {
#pragma unroll
    for (int k = 0; k < NK; ++k)
      *(float2*)&Red[k * NC + c0] = make_float2(accA[k], accB[k]);
  }
  __syncthreads();
  if (w < 2) {
    float* dst = psum + ((size_t)(bi * NSL + r0) * NK) * NC + c0;
#pragma unroll
    for (int k = 0; k < NK; ++k) {
      const float2 r = *(const float2*)&Red[k * NC + c0];
      *(float2*)&dst[k * NC] = make_float2(accA[k] + r.x, accB[k] + r.y);
    }
  }
  if (tid < NK) pcnt[(size_t)(bi * NSL + r0) * NK + tid] = (float)hist[tid];
}

// ---------------------------------------------------------------------------
// Finalize A: grid (NK, NB, NG) = 1344 blocks; each reduces 8 row-slices.
// psum2[b][g][k][c], pcnt2[b][g][k].
// ---------------------------------------------------------------------------
__global__ __launch_bounds__(256)
void proto_finalA(const float* __restrict__ psum,
                  const float* __restrict__ pcnt,
                  float* __restrict__ psum2,
                  float* __restrict__ pcnt2) {
  const int k = blockIdx.x;   // 0..20
  const int b = blockIdx.y;   // 0..7
  const int g = blockIdx.z;   // 0..7
  const int c = threadIdx.x;  // 0..255
  const int sl0 = g * (NSL / NG);
  float s = 0.f, cnt = 0.f;
#pragma unroll
  for (int j = 0; j < NSL / NG; ++j) {
    s += psum[((size_t)(b * NSL + sl0 + j) * NK + k) * NC + c];  // coalesced
    cnt += pcnt[(size_t)(b * NSL + sl0 + j) * NK + k];           // uniform
  }
  psum2[((size_t)(b * NG + g) * NK + k) * NC + c] = s;
  if (c == 0) pcnt2[(size_t)(b * NG + g) * NK + k] = cnt;
}

// ---------------------------------------------------------------------------
// Finalize B: grid (NK); L2-hot 1.4 MB.
// out[k][c] = (1/8) sum_b [sum_g psum2] / (sum_g pcnt2 + eps)
// ---------------------------------------------------------------------------
__global__ __launch_bounds__(256)
void proto_finalB(const float* __restrict__ psum2,
                  const float* __restrict__ pcnt2,
                  float* __restrict__ out) {
  const int k = blockIdx.x;
  const int c = threadIdx.x;
  float a = 0.f;
#pragma unroll
  for (int b = 0; b < NB; ++b) {
    float s = 0.f, cnt = 0.f;
#pragma unroll
    for (int g = 0; g < NG; ++g) {
      s += psum2[((size_t)(b * NG + g) * NK + k) * NC + c];
      cnt += pcnt2[(size_t)(b * NG + g) * NK + k];
    }
    a += s / (cnt + EPS);
  }
  out[(size_t)k * NC + c] = a * 0.125f;
}

extern "C" void kernel_launch(void* const* d_in, const int* in_sizes, int n_in,
                              void* d_out, int out_size, void* d_ws, size_t ws_size,
                              hipStream_t stream) {
  const float* feats = (const float*)d_in[0];
  const int* masks = (const int*)d_in[1];
  float* out = (float*)d_out;

  // ws: psum [8][64][21][256] (11.0 MB) | pcnt [8][64][21] (43 KB)
  //   | psum2 [8][8][21][256] (1.38 MB) | pcnt2 [8][8][21] (5.4 KB)
  // All regions fully overwritten before read; no memset needed.
  float* psum = (float*)d_ws;
  float* pcnt = psum + (size_t)NB * NSL * NK * NC;
  float* psum2 = pcnt + (size_t)NB * NSL * NK;
  float* pcnt2 = psum2 + (size_t)NB * NG * NK * NC;

  proto_main<<<dim3(64, NB), 256, 0, stream>>>(feats, masks, psum, pcnt);
  proto_finalA<<<dim3(NK, NB, NG), 256, 0, stream>>>(psum, pcnt, psum2, pcnt2);
  proto_finalB<<<dim3(NK), 256, 0, stream>>>(psum2, pcnt2, out);
}